// Round 10
// baseline (457.970 us; speedup 1.0000x reference)
//
#include <hip/hip_runtime.h>

#define N_NODES 50000
#define N_PAD   50016
#define N_EDGES 800000
#define HID 128
#define NCLS 10
#define NG 64
#define PWAVE 32
#define NB_SCAN ((N_NODES + 255) / 256)   // 196

// XCD-partitioned edge processing
#define EPART 8
#define PRANGE ((N_NODES + EPART - 1) / EPART)
#define ECHUNK 4096
#define NCHUNK ((N_EDGES + ECHUNK - 1) / ECHUNK)

typedef unsigned int uint32;
typedef __attribute__((ext_vector_type(8))) short bf16x8;
typedef __attribute__((ext_vector_type(4))) float f32x4;

__device__ __forceinline__ unsigned short f2bf(float f) {
    uint32 u = __float_as_uint(f);
    uint32 r = u + 0x7fffu + ((u >> 16) & 1u);   // RNE
    return (unsigned short)(r >> 16);
}
__device__ __forceinline__ float bflo(uint32 v) { return __uint_as_float(v << 16); }
__device__ __forceinline__ float bfhi(uint32 v) { return __uint_as_float(v & 0xffff0000u); }
__device__ __forceinline__ uint32 packbf(float a, float b) {
    return (uint32)f2bf(a) | ((uint32)f2bf(b) << 16);
}

// ---------------- PRE: zero deg/sums + gbounds + input conv + weight conv (1 launch) ----------------
// grid split: [0,CB) conv, [CB,CB+196) zero deg, [CB+196] zero sums,
// [CB+197, CB+393) gbounds, [CB+393, +416) wconv.

#define PRE_N4E (N_NODES * 128 / 4)
#define PRE_N4C (N_NODES * 64 / 4)
#define PRE_CB ((PRE_N4E + PRE_N4C + 255) / 256)   // 9375
#define PRE_ZB ((N_NODES + 255) / 256)             // 196
#define PRE_TOTAL (PRE_CB + PRE_ZB + 1 + PRE_ZB + 416)

__global__ __launch_bounds__(256) void pre_k(const float* __restrict__ exp_f,
                                             unsigned short* __restrict__ Xe,
                                             const float* __restrict__ cnv_f,
                                             unsigned short* __restrict__ Xc,
                                             int* __restrict__ deg,
                                             float* __restrict__ sums,       // sumD||sumT, 16384 floats
                                             const int* __restrict__ batch,
                                             int* __restrict__ gstart,
                                             const float* W1e, const float* W2e,
                                             const float* W1c, const float* W2c,
                                             const float* Wm, const float* Wp1,
                                             unsigned short* WT1e, unsigned short* WT2e,
                                             unsigned short* WT1c, unsigned short* WT2c,
                                             unsigned short* WTm1, unsigned short* WTm2,
                                             unsigned short* WTp1) {
    int b = blockIdx.x;
    int t = threadIdx.x;
    if (b < PRE_CB) {
        int i = b * 256 + t;
        const float* in;
        unsigned short* out;
        if (i < PRE_N4E) { in = exp_f; out = Xe; }
        else { i -= PRE_N4E; if (i >= PRE_N4C) return; in = cnv_f; out = Xc; }
        float4 v = *(const float4*)(in + (size_t)i * 4);
        uint2 o = {packbf(v.x, v.y), packbf(v.z, v.w)};
        *(uint2*)(out + (size_t)i * 4) = o;
        return;
    }
    b -= PRE_CB;
    if (b < PRE_ZB) {
        int i = b * 256 + t;
        if (i < N_NODES) deg[i] = 0;
        return;
    }
    b -= PRE_ZB;
    if (b == 0) {
        for (int i = t; i < 2 * NG * 128; i += 256) sums[i] = 0.f;
        return;
    }
    b -= 1;
    if (b < PRE_ZB) {
        int i = b * 256 + t;
        if (i >= N_NODES) return;
        int bb = batch[i];
        int prev = (i == 0) ? -1 : batch[i - 1];
        for (int g = prev + 1; g <= bb; g++) gstart[g] = i;
        if (i == N_NODES - 1) {
            for (int g = bb + 1; g <= NG; g++) gstart[g] = N_NODES;
        }
        return;
    }
    b -= PRE_ZB;
    // wconv: b in [0,416)
    const float* W; unsigned short* WT; int i; int K;
    if (b < 64)       { W = W1e; WT = WT1e; i = b * 256 + t;          K = 128; }
    else if (b < 128) { W = W2e; WT = WT2e; i = (b - 64) * 256 + t;   K = 128; }
    else if (b < 160) { W = W1c; WT = WT1c; i = (b - 128) * 256 + t;  K = 64;  }
    else if (b < 224) { W = W2c; WT = WT2c; i = (b - 160) * 256 + t;  K = 128; }
    else if (b < 352) {
        i = (b - 224) * 256 + t;
        int k = i >> 7, n = i & 127;
        unsigned short v = f2bf(Wm[i]);
        if (k < 128) WTm1[n * 128 + k] = v;
        else         WTm2[n * 128 + (k - 128)] = v;
        return;
    }
    else              { W = Wp1; WT = WTp1; i = (b - 352) * 256 + t;  K = 128; }
    int k = i >> 7, n = i & 127;
    if (k < K) WT[n * K + k] = f2bf(W[i]);
}

// ---------------- CSR build (XCD-partitioned by dst range) ----------------

__global__ __launch_bounds__(256) void count_part_k(const int* __restrict__ dst,
                                                    int* __restrict__ deg) {
    int part = blockIdx.x & 7;
    int chunk = blockIdx.x >> 3;
    int lo = part * PRANGE;
    int hi = min(lo + PRANGE, N_NODES);
    int e0 = chunk * ECHUNK;
    int e1 = min(e0 + ECHUNK, N_EDGES);
    for (int i = e0 + threadIdx.x; i < e1; i += 256) {
        int d = dst[i];
        if (d >= lo && d < hi) atomicAdd(&deg[d], 1);
    }
}

__global__ __launch_bounds__(256) void scatter_part_k(const int* __restrict__ src,
                                                      const int* __restrict__ dst,
                                                      int* __restrict__ cursor,
                                                      int* __restrict__ csr) {
    int part = blockIdx.x & 7;
    int chunk = blockIdx.x >> 3;
    int lo = part * PRANGE;
    int hi = min(lo + PRANGE, N_NODES);
    int e0 = chunk * ECHUNK;
    int e1 = min(e0 + ECHUNK, N_EDGES);
    for (int i = e0 + threadIdx.x; i < e1; i += 256) {
        int d = dst[i];
        if (d >= lo && d < hi) {
            int pos = atomicAdd(&cursor[d], 1);
            csr[pos] = src[i];
        }
    }
}

__device__ __forceinline__ int block_excl_scan_256(int v, int tid, int* total_out) {
    int lane = tid & 63, w = tid >> 6;
    int x = v;
#pragma unroll
    for (int off = 1; off < 64; off <<= 1) {
        int y = __shfl_up(x, off, 64);
        if (lane >= off) x += y;
    }
    __shared__ int wsum[4];
    if (lane == 63) wsum[w] = x;
    __syncthreads();
    int add = 0;
#pragma unroll
    for (int i = 0; i < 4; i++) add += (i < w) ? wsum[i] : 0;
    int total = wsum[0] + wsum[1] + wsum[2] + wsum[3];
    if (total_out) *total_out = total;
    return x - v + add;
}

__global__ __launch_bounds__(256) void scan_partial_k(const int* __restrict__ deg,
                                                      int* __restrict__ rowptr,
                                                      int* __restrict__ blocksum) {
    int tid = threadIdx.x;
    int gid = blockIdx.x * 256 + tid;
    int v = (gid < N_NODES) ? deg[gid] : 0;
    int total;
    int excl = block_excl_scan_256(v, tid, &total);
    if (gid < N_NODES) rowptr[gid] = excl;
    if (tid == 0) blocksum[blockIdx.x] = total;
}

__global__ __launch_bounds__(256) void scan_root_k(const int* __restrict__ blocksum,
                                                   int* __restrict__ blockoff,
                                                   const int* __restrict__ gstart,
                                                   float* __restrict__ invcnt) {
    int tid = threadIdx.x;
    int v = (tid < NB_SCAN) ? blocksum[tid] : 0;
    int excl = block_excl_scan_256(v, tid, nullptr);
    if (tid < NB_SCAN) blockoff[tid] = excl;
    if (tid < NG) {
        int c = gstart[tid + 1] - gstart[tid];
        invcnt[tid] = (c > 0) ? 1.0f / (float)c : 0.0f;
    }
}

__global__ __launch_bounds__(256) void scan_add_k(int* __restrict__ rowptr,
                                                  int* __restrict__ cursor,
                                                  const int* __restrict__ blockoff) {
    int gid = blockIdx.x * 256 + threadIdx.x;
    if (gid < N_NODES) {
        int r = rowptr[gid] + blockoff[blockIdx.x];
        rowptr[gid] = r;
        cursor[gid] = r;
    }
    if (gid == 0) rowptr[N_NODES] = N_EDGES;
}

// ---------------- agg-row helpers ----------------
// 128 features, 64 lanes, lane owns a bf16 pair. 16-deep unrolled gather.

__device__ __forceinline__ uint32 agg_row128(const uint32* __restrict__ X,
                                             const int* __restrict__ rowptr,
                                             const int* __restrict__ csr,
                                             int n, int lane, float scale) {
    uint32 xv = X[(size_t)n * 64 + lane];
    float a0 = scale * bflo(xv);
    float a1 = scale * bfhi(xv);
    int e = rowptr[n], e1 = rowptr[n + 1];
    for (; e + 16 <= e1; e += 16) {
        int idx[16]; uint32 vv[16];
#pragma unroll
        for (int j = 0; j < 16; j++) idx[j] = csr[e + j];
#pragma unroll
        for (int j = 0; j < 16; j++) vv[j] = X[(size_t)idx[j] * 64 + lane];
#pragma unroll
        for (int j = 0; j < 16; j++) { a0 += bflo(vv[j]); a1 += bfhi(vv[j]); }
    }
    if (e + 8 <= e1) {
        int idx[8]; uint32 vv[8];
#pragma unroll
        for (int j = 0; j < 8; j++) idx[j] = csr[e + j];
#pragma unroll
        for (int j = 0; j < 8; j++) vv[j] = X[(size_t)idx[j] * 64 + lane];
#pragma unroll
        for (int j = 0; j < 8; j++) { a0 += bflo(vv[j]); a1 += bfhi(vv[j]); }
        e += 8;
    }
    if (e + 4 <= e1) {
        int idx[4]; uint32 vv[4];
#pragma unroll
        for (int j = 0; j < 4; j++) idx[j] = csr[e + j];
#pragma unroll
        for (int j = 0; j < 4; j++) vv[j] = X[(size_t)idx[j] * 64 + lane];
#pragma unroll
        for (int j = 0; j < 4; j++) { a0 += bflo(vv[j]); a1 += bfhi(vv[j]); }
        e += 4;
    }
    for (; e < e1; e++) {
        uint32 v = X[(size_t)csr[e] * 64 + lane];
        a0 += bflo(v);
        a1 += bfhi(v);
    }
    return packbf(a0, a1);
}

// 64 features, 32 lanes (half-wave), lane32 owns a bf16 pair.
__device__ __forceinline__ uint32 agg_row64(const uint32* __restrict__ X,
                                            const int* __restrict__ rowptr,
                                            const int* __restrict__ csr,
                                            int n, int lane32, float scale) {
    uint32 xv = X[(size_t)n * 32 + lane32];
    float a0 = scale * bflo(xv);
    float a1 = scale * bfhi(xv);
    int e = rowptr[n], e1 = rowptr[n + 1];
    for (; e + 8 <= e1; e += 8) {
        int idx[8]; uint32 vv[8];
#pragma unroll
        for (int j = 0; j < 8; j++) idx[j] = csr[e + j];
#pragma unroll
        for (int j = 0; j < 8; j++) vv[j] = X[(size_t)idx[j] * 32 + lane32];
#pragma unroll
        for (int j = 0; j < 8; j++) { a0 += bflo(vv[j]); a1 += bfhi(vv[j]); }
    }
    if (e + 4 <= e1) {
        int idx[4]; uint32 vv[4];
#pragma unroll
        for (int j = 0; j < 4; j++) idx[j] = csr[e + j];
#pragma unroll
        for (int j = 0; j < 4; j++) vv[j] = X[(size_t)idx[j] * 32 + lane32];
#pragma unroll
        for (int j = 0; j < 4; j++) { a0 += bflo(vv[j]); a1 += bfhi(vv[j]); }
        e += 4;
    }
    for (; e < e1; e++) {
        uint32 v = X[(size_t)csr[e] * 32 + lane32];
        a0 += bflo(v);
        a1 += bfhi(v);
    }
    return packbf(a0, a1);
}

// ---------------- FUSED GIN layer: out = lrelu(agg(X) @ W + b) ----------------
// Block = 256 thr = 4 waves = 32 output rows. Set 1 (blk<nblk1): K=128.
// Set 2: K=K2 (128 or 64). LDS XOR-swizzle byte ^= (row&7)<<4 (G4; residual
// 2-way alias row<->row+8 is free per m136). B-frags from L2-resident WT with
// the SAME per-lane k-slot formula as A (permutation cancels in contraction).
// C/D mapping (m89/m91-verified): col = lane&15, row = (lane>>4)*4 + reg.

__global__ __launch_bounds__(256) void agg_gemm_k(const uint32* __restrict__ X1,
                                                  const float* __restrict__ eps1,
                                                  const unsigned short* __restrict__ WT1p,
                                                  const float* __restrict__ b1,
                                                  unsigned short* __restrict__ out1,
                                                  const uint32* __restrict__ X2,
                                                  const float* __restrict__ eps2,
                                                  const unsigned short* __restrict__ WT2p,
                                                  const float* __restrict__ b2,
                                                  unsigned short* __restrict__ out2,
                                                  const int* __restrict__ rowptr,
                                                  const int* __restrict__ csr,
                                                  int nblk1, int K2) {
    __shared__ uint32 lds[32 * 64];   // up to 32 rows x 128 bf16, swizzled
    int blk = blockIdx.x;
    bool second = blk >= nblk1;
    if (second) blk -= nblk1;
    const uint32* X = second ? X2 : X1;
    const float* epsp = second ? eps2 : eps1;
    const unsigned short* WT = second ? WT2p : WT1p;
    const float* bias = second ? b2 : b1;
    unsigned short* out = second ? out2 : out1;
    int K = second ? K2 : 128;

    int tid = threadIdx.x;
    int w = tid >> 6, lane = tid & 63;
    int base = blk * 32;
    float scale = 2.0f + epsp[0];

    if (K == 128) {
        // phase 1: wave w aggregates rows w*8..w*8+7
        for (int s = 0; s < 8; s++) {
            int lrow = w * 8 + s;
            int n = base + lrow;
            uint32 outv = 0;
            if (n < N_NODES) outv = agg_row128(X, rowptr, csr, n, lane, scale);
            int byte = (lrow * 256 + lane * 4) ^ ((lrow & 7) << 4);
            lds[byte >> 2] = outv;
        }
    } else {
        // K=64: two half-waves aggregate two rows per sub-iteration
        int half = lane >> 5, lane32 = lane & 31;
        for (int s = 0; s < 4; s++) {
            int lrow = w * 8 + 2 * s + half;
            int n = base + lrow;
            uint32 outv = 0;
            if (n < N_NODES) outv = agg_row64(X, rowptr, csr, n, lane32, scale);
            int byte = (lrow * 128 + lane32 * 4) ^ ((lrow & 7) << 4);
            lds[byte >> 2] = outv;
        }
    }
    __syncthreads();

    // phase 2: MFMA tile (rows base+(w&1)*16, cols (w>>1)*64)
    int m = lane & 15, g = lane >> 4;
    int lrow = (w & 1) * 16 + m;
    int row16 = base + (w & 1) * 16;
    int col16 = (w >> 1) * 64;

    f32x4 acc[4];
#pragma unroll
    for (int nt = 0; nt < 4; nt++) acc[nt] = (f32x4){0.f, 0.f, 0.f, 0.f};

    const unsigned short* bp = WT + (size_t)(col16 + m) * K + g * 8;
    int rowbytes = K * 2;  // 256 (K=128) or 128 (K=64)
    for (int k0 = 0; k0 < K; k0 += 32) {
        int ab = (lrow * rowbytes + (g * 8 + k0) * 2) ^ ((lrow & 7) << 4);
        bf16x8 af = *(const bf16x8*)((const char*)lds + ab);
#pragma unroll
        for (int nt = 0; nt < 4; nt++) {
            bf16x8 bfv = *(const bf16x8*)(bp + (size_t)nt * 16 * K + k0);
            acc[nt] = __builtin_amdgcn_mfma_f32_16x16x32_bf16(af, bfv, acc[nt], 0, 0, 0);
        }
    }

#pragma unroll
    for (int nt = 0; nt < 4; nt++) {
        int col = col16 + nt * 16 + m;
        float bv = bias[col];
#pragma unroll
        for (int r = 0; r < 4; r++) {
            int row = row16 + g * 4 + r;
            if (row < N_NODES) {
                float v = acc[nt][r] + bv;
                v = v > 0.f ? v : 0.2f * v;   // lrelu (all GIN layers)
                out[(size_t)row * 128 + col] = f2bf(v);
            }
        }
    }
}

// ---------------- MFMA bf16 GEMM (A from global; mix & head layers) ----------------

__global__ __launch_bounds__(256) void gemm_bf_k(const unsigned short* __restrict__ A1,
                                                 const unsigned short* __restrict__ WT1, int K1,
                                                 const unsigned short* __restrict__ A2,
                                                 const unsigned short* __restrict__ WT2, int K2,
                                                 const float* __restrict__ bias,
                                                 unsigned short* __restrict__ out, int act) {
    int tid = threadIdx.x;
    int w = tid >> 6, l = tid & 63;
    int row16 = blockIdx.x * 32 + (w & 1) * 16;
    int col16 = (w >> 1) * 64;
    int m = l & 15, g = l >> 4;

    f32x4 acc[4];
#pragma unroll
    for (int nt = 0; nt < 4; nt++) acc[nt] = (f32x4){0.f, 0.f, 0.f, 0.f};

    const unsigned short* A = A1;
    const unsigned short* WT = WT1;
    int K = K1;
    for (int pass = 0; pass < 2; ++pass) {
        if (pass) {
            if (A2 == nullptr) break;
            A = A2; WT = WT2; K = K2;
        }
        const unsigned short* ap = A + (size_t)(row16 + m) * K + g * 8;
        const unsigned short* bp = WT + (size_t)(col16 + m) * K + g * 8;
        for (int k0 = 0; k0 < K; k0 += 32) {
            bf16x8 af = *(const bf16x8*)(ap + k0);
#pragma unroll
            for (int nt = 0; nt < 4; nt++) {
                bf16x8 bfv = *(const bf16x8*)(bp + (size_t)nt * 16 * K + k0);
                acc[nt] = __builtin_amdgcn_mfma_f32_16x16x32_bf16(af, bfv, acc[nt], 0, 0, 0);
            }
        }
    }

#pragma unroll
    for (int nt = 0; nt < 4; nt++) {
        int col = col16 + nt * 16 + m;
        float bv = bias[col];
#pragma unroll
        for (int r = 0; r < 4; r++) {
            int row = row16 + g * 4 + r;
            if (row < N_NODES) {
                float v = acc[nt][r] + bv;
                if (act == 1) v = v > 0.f ? v : 0.2f * v;
                else if (act == 2) v = fmaxf(v, 0.f);
                out[(size_t)row * 128 + col] = f2bf(v);
            }
        }
    }
}

// ---------------- fused partial pooling over bf16 D and T ----------------

__global__ __launch_bounds__(256) void pool2_bf_k(const uint32* __restrict__ D,
                                                  const uint32* __restrict__ T,
                                                  const int* __restrict__ batch,
                                                  float* __restrict__ sumD,
                                                  float* __restrict__ sumT) {
    int wv = (blockIdx.x * 256 + threadIdx.x) >> 6;
    int f = threadIdx.x & 63;
    int i0 = wv * PWAVE;
    if (i0 >= N_NODES) return;
    int i1 = min(i0 + PWAVE, N_NODES);
    float d0 = 0.f, d1 = 0.f, t0 = 0.f, t1 = 0.f;
    int g = batch[i0];
    int i = i0;
    for (; i + 4 <= i1; i += 4) {
        int b0 = batch[i], b1 = batch[i + 1], b2 = batch[i + 2], b3 = batch[i + 3];
        uint32 dv0 = D[(size_t)i * 64 + f];
        uint32 dv1 = D[(size_t)(i + 1) * 64 + f];
        uint32 dv2 = D[(size_t)(i + 2) * 64 + f];
        uint32 dv3 = D[(size_t)(i + 3) * 64 + f];
        uint32 tv0 = T[(size_t)i * 64 + f];
        uint32 tv1 = T[(size_t)(i + 1) * 64 + f];
        uint32 tv2 = T[(size_t)(i + 2) * 64 + f];
        uint32 tv3 = T[(size_t)(i + 3) * 64 + f];
#define POOL_STEP(bg, dv, tv)                                          \
        if (bg != g) {                                                 \
            atomicAdd(&sumD[g * 128 + 2 * f], d0);                     \
            atomicAdd(&sumD[g * 128 + 2 * f + 1], d1);                 \
            atomicAdd(&sumT[g * 128 + 2 * f], t0);                     \
            atomicAdd(&sumT[g * 128 + 2 * f + 1], t1);                 \
            d0 = d1 = t0 = t1 = 0.f; g = bg;                           \
        }                                                              \
        d0 += bflo(dv); d1 += bfhi(dv);                                \
        t0 += bflo(tv); t1 += bfhi(tv);
        POOL_STEP(b0, dv0, tv0)
        POOL_STEP(b1, dv1, tv1)
        POOL_STEP(b2, dv2, tv2)
        POOL_STEP(b3, dv3, tv3)
    }
    for (; i < i1; i++) {
        int bg = batch[i];
        uint32 dv = D[(size_t)i * 64 + f];
        uint32 tv = T[(size_t)i * 64 + f];
        POOL_STEP(bg, dv, tv)
    }
#undef POOL_STEP
    atomicAdd(&sumD[g * 128 + 2 * f], d0);
    atomicAdd(&sumD[g * 128 + 2 * f + 1], d1);
    atomicAdd(&sumT[g * 128 + 2 * f], t0);
    atomicAdd(&sumT[g * 128 + 2 * f + 1], t1);
}

// ---------------- finalize ----------------

__global__ __launch_bounds__(128) void finalize_k(const float* __restrict__ sumD,
                                                  const float* __restrict__ sumT,
                                                  const float* __restrict__ invcnt,
                                                  const float* __restrict__ Wp2,
                                                  const float* __restrict__ bp2,
                                                  float* __restrict__ out) {
    __shared__ float tr[128];
    int g = blockIdx.x;
    int f = threadIdx.x;
    float ic = invcnt[g];
    out[g * 128 + f] = sumD[g * 128 + f] * ic;
    tr[f] = sumT[g * 128 + f] * ic;
    __syncthreads();
    if (f < NCLS) {
        float acc = (ic > 0.f) ? bp2[f] : 0.f;
        for (int k = 0; k < 128; k++) acc = fmaf(tr[k], Wp2[k * NCLS + f], acc);
        out[NG * 128 + g * NCLS + f] = acc;
    }
}

// ---------------- launch ----------------

extern "C" void kernel_launch(void* const* d_in, const int* in_sizes, int n_in,
                              void* d_out, int out_size, void* d_ws, size_t ws_size,
                              hipStream_t stream) {
    const float* exp_f = (const float*)d_in[0];
    const float* cnv_f = (const float*)d_in[1];
    const int*   ei    = (const int*)d_in[2];
    const int*   batch = (const int*)d_in[3];
    const float* eps1e = (const float*)d_in[4];
    const float* W1e   = (const float*)d_in[5];
    const float* b1e   = (const float*)d_in[6];
    const float* eps2e = (const float*)d_in[7];
    const float* W2e   = (const float*)d_in[8];
    const float* b2e   = (const float*)d_in[9];
    const float* eps1c = (const float*)d_in[10];
    const float* W1c   = (const float*)d_in[11];
    const float* b1c   = (const float*)d_in[12];
    const float* eps2c = (const float*)d_in[13];
    const float* W2c   = (const float*)d_in[14];
    const float* b2c   = (const float*)d_in[15];
    const float* Wm    = (const float*)d_in[16];
    const float* bm    = (const float*)d_in[17];
    const float* Wp1   = (const float*)d_in[18];
    const float* bp1   = (const float*)d_in[19];
    const float* Wp2   = (const float*)d_in[20];
    const float* bp2   = (const float*)d_in[21];
    float* out = (float*)d_out;

    char* ws = (char*)d_ws;
    size_t off = 0;
    auto alloc = [&](size_t bytes) -> void* {
        void* p = ws + off;
        off = (off + bytes + 255) & ~(size_t)255;
        return p;
    };
    int* deg      = (int*)alloc((size_t)N_NODES * 4);
    int* rowptr   = (int*)alloc((size_t)(N_NODES + 1) * 4);
    int* cursor   = (int*)alloc((size_t)N_NODES * 4);
    int* csr      = (int*)alloc((size_t)N_EDGES * 4);
    int* gstart   = (int*)alloc((NG + 1) * 4);
    float* invcnt = (float*)alloc(NG * 4);
    int* blocksum = (int*)alloc(NB_SCAN * 4);
    int* blockoff = (int*)alloc(NB_SCAN * 4);
    float* sumD   = (float*)alloc((size_t)NG * 128 * 4);   // sumT contiguous after
    float* sumT   = (float*)alloc((size_t)NG * 128 * 4);

    unsigned short* Xe = (unsigned short*)alloc((size_t)N_PAD * 128 * 2);
    unsigned short* Xc = (unsigned short*)alloc((size_t)N_PAD * 64 * 2);
    unsigned short* B  = (unsigned short*)alloc((size_t)N_PAD * 128 * 2);
    unsigned short* C  = (unsigned short*)alloc((size_t)N_PAD * 128 * 2);
    unsigned short* B2 = (unsigned short*)alloc((size_t)N_PAD * 128 * 2);
    unsigned short* C2 = (unsigned short*)alloc((size_t)N_PAD * 128 * 2);
    unsigned short* D  = (unsigned short*)alloc((size_t)N_PAD * 128 * 2);
    unsigned short* T  = (unsigned short*)alloc((size_t)N_PAD * 128 * 2);

    unsigned short* WT1e = (unsigned short*)alloc(128 * 128 * 2);
    unsigned short* WT2e = (unsigned short*)alloc(128 * 128 * 2);
    unsigned short* WT1c = (unsigned short*)alloc(128 * 64 * 2);
    unsigned short* WT2c = (unsigned short*)alloc(128 * 128 * 2);
    unsigned short* WTm1 = (unsigned short*)alloc(128 * 128 * 2);
    unsigned short* WTm2 = (unsigned short*)alloc(128 * 128 * 2);
    unsigned short* WTp1 = (unsigned short*)alloc(128 * 128 * 2);

    const int* src = ei;
    const int* dst = ei + N_EDGES;

    // 1. preprocessing mega-launch (zero deg/sums, gbounds, conv, wconv)
    pre_k<<<PRE_TOTAL, 256, 0, stream>>>(exp_f, Xe, cnv_f, Xc, deg, sumD, batch, gstart,
                                         W1e, W2e, W1c, W2c, Wm, Wp1,
                                         WT1e, WT2e, WT1c, WT2c, WTm1, WTm2, WTp1);
    // 2-6. CSR build
    count_part_k<<<NCHUNK * EPART, 256, 0, stream>>>(dst, deg);
    scan_partial_k<<<NB_SCAN, 256, 0, stream>>>(deg, rowptr, blocksum);
    scan_root_k<<<1, 256, 0, stream>>>(blocksum, blockoff, gstart, invcnt);
    scan_add_k<<<NB_SCAN, 256, 0, stream>>>(rowptr, cursor, blockoff);
    scatter_part_k<<<NCHUNK * EPART, 256, 0, stream>>>(src, dst, cursor, csr);

    const int GEMM_GRID = (N_NODES + 31) / 32;  // 1563

    // 7. layer 1: exp (K=128 fused) + cnv (K=64 fused), one launch
    agg_gemm_k<<<2 * GEMM_GRID, 256, 0, stream>>>((const uint32*)Xe, eps1e, WT1e, b1e, B,
                                                  (const uint32*)Xc, eps1c, WT1c, b1c, C,
                                                  rowptr, csr, GEMM_GRID, 64);
    // 8. layer 2: exp + cnv, one launch
    agg_gemm_k<<<2 * GEMM_GRID, 256, 0, stream>>>((const uint32*)B, eps2e, WT2e, b2e, B2,
                                                  (const uint32*)C, eps2c, WT2c, b2c, C2,
                                                  rowptr, csr, GEMM_GRID, 128);
    // 9. mix: D = lrelu(B2@Wm_top + C2@Wm_bot + bm)
    gemm_bf_k<<<GEMM_GRID, 256, 0, stream>>>(B2, WTm1, 128, C2, WTm2, 128, bm, D, 1);
    // 10. head pre-pool: T = relu(D@Wp1+bp1)
    gemm_bf_k<<<GEMM_GRID, 256, 0, stream>>>(D, WTp1, 128, nullptr, nullptr, 0, bp1, T, 2);
    // 11-12. pooling + finalize
    const int POOL_GRID = ((N_NODES + PWAVE - 1) / PWAVE * 64 + 255) / 256;
    pool2_bf_k<<<POOL_GRID, 256, 0, stream>>>((const uint32*)D, (const uint32*)T,
                                              batch, sumD, sumT);
    finalize_k<<<NG, 128, 0, stream>>>(sumD, sumT, invcnt, Wp2, bp2, out);
}

// Round 11
// 426.248 us; speedup vs baseline: 1.0744x; 1.0744x over previous
//
#include <hip/hip_runtime.h>

#define N_NODES 50000
#define N_PAD   50016
#define N_EDGES 800000
#define HID 128
#define NCLS 10
#define NG 64
#define NB_SCAN ((N_NODES + 255) / 256)   // 196

// XCD-partitioned edge processing
#define EPART 8
#define PRANGE ((N_NODES + EPART - 1) / EPART)
#define ECHUNK 4096
#define NCHUNK ((N_EDGES + ECHUNK - 1) / ECHUNK)

typedef unsigned int uint32;
typedef __attribute__((ext_vector_type(8))) short bf16x8;
typedef __attribute__((ext_vector_type(4))) float f32x4;

__device__ __forceinline__ unsigned short f2bf(float f) {
    uint32 u = __float_as_uint(f);
    uint32 r = u + 0x7fffu + ((u >> 16) & 1u);   // RNE
    return (unsigned short)(r >> 16);
}
__device__ __forceinline__ float bflo(uint32 v) { return __uint_as_float(v << 16); }
__device__ __forceinline__ float bfhi(uint32 v) { return __uint_as_float(v & 0xffff0000u); }
__device__ __forceinline__ uint32 packbf(float a, float b) {
    return (uint32)f2bf(a) | ((uint32)f2bf(b) << 16);
}

// ---------------- PRE: zero deg/sums + gbounds + input conv + weight conv (1 launch) ----------------

#define PRE_N4E (N_NODES * 128 / 4)
#define PRE_N4C (N_NODES * 64 / 4)
#define PRE_CB ((PRE_N4E + PRE_N4C + 255) / 256)   // 9375
#define PRE_ZB ((N_NODES + 255) / 256)             // 196
#define PRE_TOTAL (PRE_CB + PRE_ZB + 1 + PRE_ZB + 416)

__global__ __launch_bounds__(256) void pre_k(const float* __restrict__ exp_f,
                                             unsigned short* __restrict__ Xe,
                                             const float* __restrict__ cnv_f,
                                             unsigned short* __restrict__ Xc,
                                             int* __restrict__ deg,
                                             float* __restrict__ sums,       // sumD||sumT
                                             const int* __restrict__ batch,
                                             int* __restrict__ gstart,
                                             const float* W1e, const float* W2e,
                                             const float* W1c, const float* W2c,
                                             const float* Wm, const float* Wp1,
                                             unsigned short* WT1e, unsigned short* WT2e,
                                             unsigned short* WT1c, unsigned short* WT2c,
                                             unsigned short* WTm1, unsigned short* WTm2,
                                             unsigned short* WTp1) {
    int b = blockIdx.x;
    int t = threadIdx.x;
    if (b < PRE_CB) {
        int i = b * 256 + t;
        const float* in;
        unsigned short* out;
        if (i < PRE_N4E) { in = exp_f; out = Xe; }
        else { i -= PRE_N4E; if (i >= PRE_N4C) return; in = cnv_f; out = Xc; }
        float4 v = *(const float4*)(in + (size_t)i * 4);
        uint2 o = {packbf(v.x, v.y), packbf(v.z, v.w)};
        *(uint2*)(out + (size_t)i * 4) = o;
        return;
    }
    b -= PRE_CB;
    if (b < PRE_ZB) {
        int i = b * 256 + t;
        if (i < N_NODES) deg[i] = 0;
        return;
    }
    b -= PRE_ZB;
    if (b == 0) {
        for (int i = t; i < 2 * NG * 128; i += 256) sums[i] = 0.f;
        return;
    }
    b -= 1;
    if (b < PRE_ZB) {
        int i = b * 256 + t;
        if (i >= N_NODES) return;
        int bb = batch[i];
        int prev = (i == 0) ? -1 : batch[i - 1];
        for (int g = prev + 1; g <= bb; g++) gstart[g] = i;
        if (i == N_NODES - 1) {
            for (int g = bb + 1; g <= NG; g++) gstart[g] = N_NODES;
        }
        return;
    }
    b -= PRE_ZB;
    const float* W; unsigned short* WT; int i; int K;
    if (b < 64)       { W = W1e; WT = WT1e; i = b * 256 + t;          K = 128; }
    else if (b < 128) { W = W2e; WT = WT2e; i = (b - 64) * 256 + t;   K = 128; }
    else if (b < 160) { W = W1c; WT = WT1c; i = (b - 128) * 256 + t;  K = 64;  }
    else if (b < 224) { W = W2c; WT = WT2c; i = (b - 160) * 256 + t;  K = 128; }
    else if (b < 352) {
        i = (b - 224) * 256 + t;
        int k = i >> 7, n = i & 127;
        unsigned short v = f2bf(Wm[i]);
        if (k < 128) WTm1[n * 128 + k] = v;
        else         WTm2[n * 128 + (k - 128)] = v;
        return;
    }
    else              { W = Wp1; WT = WTp1; i = (b - 352) * 256 + t;  K = 128; }
    int k = i >> 7, n = i & 127;
    if (k < K) WT[n * K + k] = f2bf(W[i]);
}

// ---------------- CSR build (XCD-partitioned by dst range) ----------------

__global__ __launch_bounds__(256) void count_part_k(const int* __restrict__ dst,
                                                    int* __restrict__ deg) {
    int part = blockIdx.x & 7;
    int chunk = blockIdx.x >> 3;
    int lo = part * PRANGE;
    int hi = min(lo + PRANGE, N_NODES);
    int e0 = chunk * ECHUNK;
    int e1 = min(e0 + ECHUNK, N_EDGES);
    for (int i = e0 + threadIdx.x; i < e1; i += 256) {
        int d = dst[i];
        if (d >= lo && d < hi) atomicAdd(&deg[d], 1);
    }
}

__global__ __launch_bounds__(256) void scatter_part_k(const int* __restrict__ src,
                                                      const int* __restrict__ dst,
                                                      int* __restrict__ cursor,
                                                      int* __restrict__ csr) {
    int part = blockIdx.x & 7;
    int chunk = blockIdx.x >> 3;
    int lo = part * PRANGE;
    int hi = min(lo + PRANGE, N_NODES);
    int e0 = chunk * ECHUNK;
    int e1 = min(e0 + ECHUNK, N_EDGES);
    for (int i = e0 + threadIdx.x; i < e1; i += 256) {
        int d = dst[i];
        if (d >= lo && d < hi) {
            int pos = atomicAdd(&cursor[d], 1);
            csr[pos] = src[i];
        }
    }
}

__device__ __forceinline__ int block_excl_scan_256(int v, int tid, int* total_out) {
    int lane = tid & 63, w = tid >> 6;
    int x = v;
#pragma unroll
    for (int off = 1; off < 64; off <<= 1) {
        int y = __shfl_up(x, off, 64);
        if (lane >= off) x += y;
    }
    __shared__ int wsum[4];
    if (lane == 63) wsum[w] = x;
    __syncthreads();
    int add = 0;
#pragma unroll
    for (int i = 0; i < 4; i++) add += (i < w) ? wsum[i] : 0;
    int total = wsum[0] + wsum[1] + wsum[2] + wsum[3];
    if (total_out) *total_out = total;
    return x - v + add;
}

__global__ __launch_bounds__(256) void scan_partial_k(const int* __restrict__ deg,
                                                      int* __restrict__ rowptr,
                                                      int* __restrict__ blocksum) {
    int tid = threadIdx.x;
    int gid = blockIdx.x * 256 + tid;
    int v = (gid < N_NODES) ? deg[gid] : 0;
    int total;
    int excl = block_excl_scan_256(v, tid, &total);
    if (gid < N_NODES) rowptr[gid] = excl;
    if (tid == 0) blocksum[blockIdx.x] = total;
}

__global__ __launch_bounds__(256) void scan_root_k(const int* __restrict__ blocksum,
                                                   int* __restrict__ blockoff,
                                                   const int* __restrict__ gstart,
                                                   float* __restrict__ invcnt) {
    int tid = threadIdx.x;
    int v = (tid < NB_SCAN) ? blocksum[tid] : 0;
    int excl = block_excl_scan_256(v, tid, nullptr);
    if (tid < NB_SCAN) blockoff[tid] = excl;
    if (tid < NG) {
        int c = gstart[tid + 1] - gstart[tid];
        invcnt[tid] = (c > 0) ? 1.0f / (float)c : 0.0f;
    }
}

__global__ __launch_bounds__(256) void scan_add_k(int* __restrict__ rowptr,
                                                  int* __restrict__ cursor,
                                                  const int* __restrict__ blockoff) {
    int gid = blockIdx.x * 256 + threadIdx.x;
    if (gid < N_NODES) {
        int r = rowptr[gid] + blockoff[blockIdx.x];
        rowptr[gid] = r;
        cursor[gid] = r;
    }
    if (gid == 0) rowptr[N_NODES] = N_EDGES;
}

// ---------------- agg-row helpers (8-deep unroll; 16-deep regressed occupancy r10) ----------------

__device__ __forceinline__ uint32 agg_row128(const uint32* __restrict__ X,
                                             const int* __restrict__ rowptr,
                                             const int* __restrict__ csr,
                                             int n, int lane, float scale) {
    uint32 xv = X[(size_t)n * 64 + lane];
    float a0 = scale * bflo(xv);
    float a1 = scale * bfhi(xv);
    int e = rowptr[n], e1 = rowptr[n + 1];
    for (; e + 8 <= e1; e += 8) {
        int idx[8]; uint32 vv[8];
#pragma unroll
        for (int j = 0; j < 8; j++) idx[j] = csr[e + j];
#pragma unroll
        for (int j = 0; j < 8; j++) vv[j] = X[(size_t)idx[j] * 64 + lane];
#pragma unroll
        for (int j = 0; j < 8; j++) { a0 += bflo(vv[j]); a1 += bfhi(vv[j]); }
    }
    if (e + 4 <= e1) {
        int idx[4]; uint32 vv[4];
#pragma unroll
        for (int j = 0; j < 4; j++) idx[j] = csr[e + j];
#pragma unroll
        for (int j = 0; j < 4; j++) vv[j] = X[(size_t)idx[j] * 64 + lane];
#pragma unroll
        for (int j = 0; j < 4; j++) { a0 += bflo(vv[j]); a1 += bfhi(vv[j]); }
        e += 4;
    }
    for (; e < e1; e++) {
        uint32 v = X[(size_t)csr[e] * 64 + lane];
        a0 += bflo(v);
        a1 += bfhi(v);
    }
    return packbf(a0, a1);
}

__device__ __forceinline__ uint32 agg_row64(const uint32* __restrict__ X,
                                            const int* __restrict__ rowptr,
                                            const int* __restrict__ csr,
                                            int n, int lane32, float scale) {
    uint32 xv = X[(size_t)n * 32 + lane32];
    float a0 = scale * bflo(xv);
    float a1 = scale * bfhi(xv);
    int e = rowptr[n], e1 = rowptr[n + 1];
    for (; e + 8 <= e1; e += 8) {
        int idx[8]; uint32 vv[8];
#pragma unroll
        for (int j = 0; j < 8; j++) idx[j] = csr[e + j];
#pragma unroll
        for (int j = 0; j < 8; j++) vv[j] = X[(size_t)idx[j] * 32 + lane32];
#pragma unroll
        for (int j = 0; j < 8; j++) { a0 += bflo(vv[j]); a1 += bfhi(vv[j]); }
    }
    if (e + 4 <= e1) {
        int idx[4]; uint32 vv[4];
#pragma unroll
        for (int j = 0; j < 4; j++) idx[j] = csr[e + j];
#pragma unroll
        for (int j = 0; j < 4; j++) vv[j] = X[(size_t)idx[j] * 32 + lane32];
#pragma unroll
        for (int j = 0; j < 4; j++) { a0 += bflo(vv[j]); a1 += bfhi(vv[j]); }
        e += 4;
    }
    for (; e < e1; e++) {
        uint32 v = X[(size_t)csr[e] * 32 + lane32];
        a0 += bflo(v);
        a1 += bfhi(v);
    }
    return packbf(a0, a1);
}

// ---------------- FUSED GIN layer: out = lrelu(agg(X) @ W + b) ----------------
// Block = 256 thr = 4 waves = 32 rows. LDS XOR-swizzle byte ^= (row&7)<<4 (G4).
// B-frags use the SAME per-lane k-slot formula as A (permutation cancels).
// C/D mapping (m89/m91-verified): col = lane&15, row = (lane>>4)*4 + reg.

__global__ __launch_bounds__(256) void agg_gemm_k(const uint32* __restrict__ X1,
                                                  const float* __restrict__ eps1,
                                                  const unsigned short* __restrict__ WT1p,
                                                  const float* __restrict__ b1,
                                                  unsigned short* __restrict__ out1,
                                                  const uint32* __restrict__ X2,
                                                  const float* __restrict__ eps2,
                                                  const unsigned short* __restrict__ WT2p,
                                                  const float* __restrict__ b2,
                                                  unsigned short* __restrict__ out2,
                                                  const int* __restrict__ rowptr,
                                                  const int* __restrict__ csr,
                                                  int nblk1, int K2) {
    __shared__ uint32 lds[32 * 64];
    int blk = blockIdx.x;
    bool second = blk >= nblk1;
    if (second) blk -= nblk1;
    const uint32* X = second ? X2 : X1;
    const float* epsp = second ? eps2 : eps1;
    const unsigned short* WT = second ? WT2p : WT1p;
    const float* bias = second ? b2 : b1;
    unsigned short* out = second ? out2 : out1;
    int K = second ? K2 : 128;

    int tid = threadIdx.x;
    int w = tid >> 6, lane = tid & 63;
    int base = blk * 32;
    float scale = 2.0f + epsp[0];

    if (K == 128) {
        for (int s = 0; s < 8; s++) {
            int lrow = w * 8 + s;
            int n = base + lrow;
            uint32 outv = 0;
            if (n < N_NODES) outv = agg_row128(X, rowptr, csr, n, lane, scale);
            int byte = (lrow * 256 + lane * 4) ^ ((lrow & 7) << 4);
            lds[byte >> 2] = outv;
        }
    } else {
        int half = lane >> 5, lane32 = lane & 31;
        for (int s = 0; s < 4; s++) {
            int lrow = w * 8 + 2 * s + half;
            int n = base + lrow;
            uint32 outv = 0;
            if (n < N_NODES) outv = agg_row64(X, rowptr, csr, n, lane32, scale);
            int byte = (lrow * 128 + lane32 * 4) ^ ((lrow & 7) << 4);
            lds[byte >> 2] = outv;
        }
    }
    __syncthreads();

    int m = lane & 15, g = lane >> 4;
    int lrow = (w & 1) * 16 + m;
    int row16 = base + (w & 1) * 16;
    int col16 = (w >> 1) * 64;

    f32x4 acc[4];
#pragma unroll
    for (int nt = 0; nt < 4; nt++) acc[nt] = (f32x4){0.f, 0.f, 0.f, 0.f};

    const unsigned short* bp = WT + (size_t)(col16 + m) * K + g * 8;
    int rowbytes = K * 2;
    for (int k0 = 0; k0 < K; k0 += 32) {
        int ab = (lrow * rowbytes + (g * 8 + k0) * 2) ^ ((lrow & 7) << 4);
        bf16x8 af = *(const bf16x8*)((const char*)lds + ab);
#pragma unroll
        for (int nt = 0; nt < 4; nt++) {
            bf16x8 bfv = *(const bf16x8*)(bp + (size_t)nt * 16 * K + k0);
            acc[nt] = __builtin_amdgcn_mfma_f32_16x16x32_bf16(af, bfv, acc[nt], 0, 0, 0);
        }
    }

#pragma unroll
    for (int nt = 0; nt < 4; nt++) {
        int col = col16 + nt * 16 + m;
        float bv = bias[col];
#pragma unroll
        for (int r = 0; r < 4; r++) {
            int row = row16 + g * 4 + r;
            if (row < N_NODES) {
                float v = acc[nt][r] + bv;
                v = v > 0.f ? v : 0.2f * v;
                out[(size_t)row * 128 + col] = f2bf(v);
            }
        }
    }
}

// ---------------- FUSED mix + head + pool ----------------
// D = lrelu(B2@Wm1 + C2@Wm2 + bm); T = relu(D@Wp1 + bp1); pool both per graph.
// D and T are consumed row-locally only -> never materialized in global.
// Block = 32 rows. D/T tiles live in swizzled bf16 LDS; pool phase reduces
// columns with graph-boundary flush (sums zeroed in pre_k).

__global__ __launch_bounds__(256) void mix_head_pool_k(const unsigned short* __restrict__ B2,
                                                       const unsigned short* __restrict__ WTm1,
                                                       const unsigned short* __restrict__ C2,
                                                       const unsigned short* __restrict__ WTm2,
                                                       const float* __restrict__ bm,
                                                       const unsigned short* __restrict__ WTp1,
                                                       const float* __restrict__ bp1,
                                                       const int* __restrict__ batch,
                                                       float* __restrict__ sumD,
                                                       float* __restrict__ sumT,
                                                       float* __restrict__ outD) {
    __shared__ uint32 Dl[32 * 64];
    __shared__ uint32 Tl[32 * 64];
    __shared__ int bat[32];
    int tid = threadIdx.x;
    int w = tid >> 6, lane = tid & 63;
    int base = blockIdx.x * 32;
    int m = lane & 15, g = lane >> 4;
    int row16loc = (w & 1) * 16;
    int row16 = base + row16loc;
    int col16 = (w >> 1) * 64;

    if (tid < 32) bat[tid] = (base + tid < N_NODES) ? batch[base + tid] : -1;

    // pass A: D tile
    f32x4 acc[4];
#pragma unroll
    for (int nt = 0; nt < 4; nt++) acc[nt] = (f32x4){0.f, 0.f, 0.f, 0.f};
    for (int pass = 0; pass < 2; ++pass) {
        const unsigned short* A = pass ? C2 : B2;
        const unsigned short* WT = pass ? WTm2 : WTm1;
        const unsigned short* ap = A + (size_t)(row16 + m) * 128 + g * 8;
        const unsigned short* bp = WT + (size_t)(col16 + m) * 128 + g * 8;
#pragma unroll
        for (int k0 = 0; k0 < 128; k0 += 32) {
            bf16x8 af = *(const bf16x8*)(ap + k0);
#pragma unroll
            for (int nt = 0; nt < 4; nt++) {
                bf16x8 bfv = *(const bf16x8*)(bp + (size_t)nt * 16 * 128 + k0);
                acc[nt] = __builtin_amdgcn_mfma_f32_16x16x32_bf16(af, bfv, acc[nt], 0, 0, 0);
            }
        }
    }
#pragma unroll
    for (int nt = 0; nt < 4; nt++) {
        int col = col16 + nt * 16 + m;
        float bv = bm[col];
#pragma unroll
        for (int r = 0; r < 4; r++) {
            int rl = row16loc + g * 4 + r;
            float v = acc[nt][r] + bv;
            v = v > 0.f ? v : 0.2f * v;
            int byte = (rl * 256 + col * 2) ^ ((rl & 7) << 4);
            *(unsigned short*)((char*)Dl + byte) = f2bf(v);
        }
    }
    __syncthreads();

    // pass B: T tile = relu(D @ Wp1 + bp1), A-frags from Dl
    f32x4 acc2[4];
#pragma unroll
    for (int nt = 0; nt < 4; nt++) acc2[nt] = (f32x4){0.f, 0.f, 0.f, 0.f};
    {
        int lrowA = row16loc + m;
        const unsigned short* bp = WTp1 + (size_t)(col16 + m) * 128 + g * 8;
#pragma unroll
        for (int k0 = 0; k0 < 128; k0 += 32) {
            int ab = (lrowA * 256 + (g * 8 + k0) * 2) ^ ((lrowA & 7) << 4);
            bf16x8 af = *(const bf16x8*)((const char*)Dl + ab);
#pragma unroll
            for (int nt = 0; nt < 4; nt++) {
                bf16x8 bfv = *(const bf16x8*)(bp + (size_t)nt * 16 * 128 + k0);
                acc2[nt] = __builtin_amdgcn_mfma_f32_16x16x32_bf16(af, bfv, acc2[nt], 0, 0, 0);
            }
        }
    }
#pragma unroll
    for (int nt = 0; nt < 4; nt++) {
        int col = col16 + nt * 16 + m;
        float bv = bp1[col];
#pragma unroll
        for (int r = 0; r < 4; r++) {
            int rl = row16loc + g * 4 + r;
            float v = fmaxf(acc2[nt][r] + bv, 0.f);
            int byte = (rl * 256 + col * 2) ^ ((rl & 7) << 4);
            *(unsigned short*)((char*)Tl + byte) = f2bf(v);
        }
    }
    __syncthreads();

    // pass C: pool (threads 0-127): col pair cp, rows half*16..+15
    if (tid < 128) {
        int cp = tid & 63;
        int half = tid >> 6;
        int r0 = half * 16;
        int nrow = min(32, N_NODES - base);
        int rend = min(r0 + 16, nrow);
        if (r0 < rend) {
            float d0 = 0.f, d1 = 0.f, t0 = 0.f, t1 = 0.f;
            int gcur = bat[r0];
            for (int r = r0; r < rend; r++) {
                int bg = bat[r];
                if (bg != gcur) {
                    atomicAdd(&sumD[gcur * 128 + 2 * cp], d0);
                    atomicAdd(&sumD[gcur * 128 + 2 * cp + 1], d1);
                    atomicAdd(&sumT[gcur * 128 + 2 * cp], t0);
                    atomicAdd(&sumT[gcur * 128 + 2 * cp + 1], t1);
                    d0 = d1 = t0 = t1 = 0.f; gcur = bg;
                }
                int byte = (r * 256 + cp * 4) ^ ((r & 7) << 4);
                uint32 dv = *(const uint32*)((const char*)Dl + byte);
                uint32 tv = *(const uint32*)((const char*)Tl + byte);
                d0 += bflo(dv); d1 += bfhi(dv);
                t0 += bflo(tv); t1 += bfhi(tv);
            }
            atomicAdd(&sumD[gcur * 128 + 2 * cp], d0);
            atomicAdd(&sumD[gcur * 128 + 2 * cp + 1], d1);
            atomicAdd(&sumT[gcur * 128 + 2 * cp], t0);
            atomicAdd(&sumT[gcur * 128 + 2 * cp + 1], t1);
        }
    }
    (void)outD;
}

// ---------------- finalize ----------------

__global__ __launch_bounds__(128) void finalize_k(const float* __restrict__ sumD,
                                                  const float* __restrict__ sumT,
                                                  const float* __restrict__ invcnt,
                                                  const float* __restrict__ Wp2,
                                                  const float* __restrict__ bp2,
                                                  float* __restrict__ out) {
    __shared__ float tr[128];
    int g = blockIdx.x;
    int f = threadIdx.x;
    float ic = invcnt[g];
    out[g * 128 + f] = sumD[g * 128 + f] * ic;
    tr[f] = sumT[g * 128 + f] * ic;
    __syncthreads();
    if (f < NCLS) {
        float acc = (ic > 0.f) ? bp2[f] : 0.f;
        for (int k = 0; k < 128; k++) acc = fmaf(tr[k], Wp2[k * NCLS + f], acc);
        out[NG * 128 + g * NCLS + f] = acc;
    }
}

// ---------------- launch ----------------

extern "C" void kernel_launch(void* const* d_in, const int* in_sizes, int n_in,
                              void* d_out, int out_size, void* d_ws, size_t ws_size,
                              hipStream_t stream) {
    const float* exp_f = (const float*)d_in[0];
    const float* cnv_f = (const float*)d_in[1];
    const int*   ei    = (const int*)d_in[2];
    const int*   batch = (const int*)d_in[3];
    const float* eps1e = (const float*)d_in[4];
    const float* W1e   = (const float*)d_in[5];
    const float* b1e   = (const float*)d_in[6];
    const float* eps2e = (const float*)d_in[7];
    const float* W2e   = (const float*)d_in[8];
    const float* b2e   = (const float*)d_in[9];
    const float* eps1c = (const float*)d_in[10];
    const float* W1c   = (const float*)d_in[11];
    const float* b1c   = (const float*)d_in[12];
    const float* eps2c = (const float*)d_in[13];
    const float* W2c   = (const float*)d_in[14];
    const float* b2c   = (const float*)d_in[15];
    const float* Wm    = (const float*)d_in[16];
    const float* bm    = (const float*)d_in[17];
    const float* Wp1   = (const float*)d_in[18];
    const float* bp1   = (const float*)d_in[19];
    const float* Wp2   = (const float*)d_in[20];
    const float* bp2   = (const float*)d_in[21];
    float* out = (float*)d_out;

    char* ws = (char*)d_ws;
    size_t off = 0;
    auto alloc = [&](size_t bytes) -> void* {
        void* p = ws + off;
        off = (off + bytes + 255) & ~(size_t)255;
        return p;
    };
    int* deg      = (int*)alloc((size_t)N_NODES * 4);
    int* rowptr   = (int*)alloc((size_t)(N_NODES + 1) * 4);
    int* cursor   = (int*)alloc((size_t)N_NODES * 4);
    int* csr      = (int*)alloc((size_t)N_EDGES * 4);
    int* gstart   = (int*)alloc((NG + 1) * 4);
    float* invcnt = (float*)alloc(NG * 4);
    int* blocksum = (int*)alloc(NB_SCAN * 4);
    int* blockoff = (int*)alloc(NB_SCAN * 4);
    float* sumD   = (float*)alloc((size_t)NG * 128 * 4);   // sumT contiguous after
    float* sumT   = (float*)alloc((size_t)NG * 128 * 4);

    unsigned short* Xe = (unsigned short*)alloc((size_t)N_PAD * 128 * 2);
    unsigned short* Xc = (unsigned short*)alloc((size_t)N_PAD * 64 * 2);
    unsigned short* B  = (unsigned short*)alloc((size_t)N_PAD * 128 * 2);
    unsigned short* C  = (unsigned short*)alloc((size_t)N_PAD * 128 * 2);
    unsigned short* B2 = (unsigned short*)alloc((size_t)N_PAD * 128 * 2);
    unsigned short* C2 = (unsigned short*)alloc((size_t)N_PAD * 128 * 2);

    unsigned short* WT1e = (unsigned short*)alloc(128 * 128 * 2);
    unsigned short* WT2e = (unsigned short*)alloc(128 * 128 * 2);
    unsigned short* WT1c = (unsigned short*)alloc(128 * 64 * 2);
    unsigned short* WT2c = (unsigned short*)alloc(128 * 128 * 2);
    unsigned short* WTm1 = (unsigned short*)alloc(128 * 128 * 2);
    unsigned short* WTm2 = (unsigned short*)alloc(128 * 128 * 2);
    unsigned short* WTp1 = (unsigned short*)alloc(128 * 128 * 2);

    const int* src = ei;
    const int* dst = ei + N_EDGES;

    // 1. preprocessing mega-launch
    pre_k<<<PRE_TOTAL, 256, 0, stream>>>(exp_f, Xe, cnv_f, Xc, deg, sumD, batch, gstart,
                                         W1e, W2e, W1c, W2c, Wm, Wp1,
                                         WT1e, WT2e, WT1c, WT2c, WTm1, WTm2, WTp1);
    // 2-6. CSR build
    count_part_k<<<NCHUNK * EPART, 256, 0, stream>>>(dst, deg);
    scan_partial_k<<<NB_SCAN, 256, 0, stream>>>(deg, rowptr, blocksum);
    scan_root_k<<<1, 256, 0, stream>>>(blocksum, blockoff, gstart, invcnt);
    scan_add_k<<<NB_SCAN, 256, 0, stream>>>(rowptr, cursor, blockoff);
    scatter_part_k<<<NCHUNK * EPART, 256, 0, stream>>>(src, dst, cursor, csr);

    const int GEMM_GRID = (N_NODES + 31) / 32;  // 1563

    // 7. layer 1: exp (K=128) + cnv (K=64), one fused launch
    agg_gemm_k<<<2 * GEMM_GRID, 256, 0, stream>>>((const uint32*)Xe, eps1e, WT1e, b1e, B,
                                                  (const uint32*)Xc, eps1c, WT1c, b1c, C,
                                                  rowptr, csr, GEMM_GRID, 64);
    // 8. layer 2: exp + cnv, one fused launch
    agg_gemm_k<<<2 * GEMM_GRID, 256, 0, stream>>>((const uint32*)B, eps2e, WT2e, b2e, B2,
                                                  (const uint32*)C, eps2c, WT2c, b2c, C2,
                                                  rowptr, csr, GEMM_GRID, 128);
    // 9. mix + head + pool fused (D, T never hit global)
    mix_head_pool_k<<<GEMM_GRID, 256, 0, stream>>>(B2, WTm1, C2, WTm2, bm, WTp1, bp1,
                                                   batch, sumD, sumT, nullptr);
    // 10. finalize
    finalize_k<<<NG, 128, 0, stream>>>(sumD, sumT, invcnt, Wp2, bp2, out);
}